// Round 4
// baseline (370.505 us; speedup 1.0000x reference)
//
#include <hip/hip_runtime.h>
#include <stdint.h>

#define F_DIM 768
#define E_DIM 512
#define N_ROWS 8192
#define M_ROWS 16384
#define T_ROWS (N_ROWS + M_ROWS)  // 24576

typedef __attribute__((ext_vector_type(4))) float f32x4;
typedef __attribute__((ext_vector_type(8))) __bf16 bf16x8;

__device__ __forceinline__ uint16_t f2bf(float f) {
  uint32_t u = __builtin_bit_cast(uint32_t, f);
  return (uint16_t)((u + 0x7FFFu + ((u >> 16) & 1u)) >> 16);
}

#define GLOAD_LDS16(g, l) __builtin_amdgcn_global_load_lds(                 \
    (const __attribute__((address_space(1))) void*)(g),                     \
    (__attribute__((address_space(3))) void*)(l), 16, 0, 0)

// ---------------------------------------------------------------------------
// fp32 -> bf16 conversion, 8 elems/thread/iter, grid-stride. BW-bound.
// ---------------------------------------------------------------------------
__global__ __launch_bounds__(256) void cvt_f32_bf16(
    const float* __restrict__ src, uint16_t* __restrict__ dst, int n8) {
  int i = blockIdx.x * 256 + threadIdx.x;
  const int stride = gridDim.x * 256;
  for (; i < n8; i += stride) {
    const float4 lo = *(const float4*)(src + (size_t)i * 8);
    const float4 hi = *(const float4*)(src + (size_t)i * 8 + 4);
    uint4 pk;
    pk.x = f2bf(lo.x) | ((uint32_t)f2bf(lo.y) << 16);
    pk.y = f2bf(lo.z) | ((uint32_t)f2bf(lo.w) << 16);
    pk.z = f2bf(hi.x) | ((uint32_t)f2bf(hi.y) << 16);
    pk.w = f2bf(hi.z) | ((uint32_t)f2bf(hi.w) << 16);
    *(uint4*)(dst + (size_t)i * 8) = pk;
  }
}

// ---------------------------------------------------------------------------
// Combined embed GEMM: Eg[row][e] = sum_f Cat[row][f]*gwb[e][f] + gb[e].
// bf16 in (gload_lds direct, pre-swizzled source), bf16 out, bias fused.
// 128x128 tile, BK=64, 4 waves (2x2), m97-style 2-barrier loop. K=768.
// ---------------------------------------------------------------------------
__global__ __launch_bounds__(256) void embed_gemm_bf(
    const uint16_t* __restrict__ cat, const uint16_t* __restrict__ gwb,
    const float* __restrict__ gb, uint16_t* __restrict__ out) {
  __shared__ uint4 smem4[2048];  // A: [0,16K), B: [16K,32K)
  char* smc = (char*)smem4;
  const int t = threadIdx.x;
  const int l = t & 63, w = t >> 6, wm = w >> 1, wn = w & 1;
  const int bx = blockIdx.x, by = blockIdx.y;
  const int g = l >> 4, x7 = l & 7, l15 = l & 15;

  f32x4 acc[4][4];
#pragma unroll
  for (int a_ = 0; a_ < 4; ++a_)
#pragma unroll
    for (int b_ = 0; b_ < 4; ++b_) acc[a_][b_] = (f32x4){0.f, 0.f, 0.f, 0.f};

  const int rr0 = t >> 3, ss = t & 7;
  const int s0 = ss ^ (rr0 & 7);
  const uint16_t* gA = cat + (size_t)(bx * 128 + rr0) * F_DIM + s0 * 8;
  const uint16_t* gB = gwb + (size_t)(by * 128 + rr0) * F_DIM + s0 * 8;
  char* ldsA = smc + t * 16;
  char* ldsB = smc + 16384 + t * 16;

  for (int kk = 0; kk < F_DIM; kk += 64) {
    __syncthreads();
#pragma unroll
    for (int i = 0; i < 4; ++i) {
      GLOAD_LDS16(gA + (size_t)i * 32 * F_DIM + kk, ldsA + i * 4096);
      GLOAD_LDS16(gB + (size_t)i * 32 * F_DIM + kk, ldsB + i * 4096);
    }
    __syncthreads();
#pragma unroll
    for (int ks = 0; ks < 2; ++ks) {
      const int slotoff = ((ks * 4 + g) ^ x7) << 4;
      bf16x8 af[4], bfr[4];
#pragma unroll
      for (int fm = 0; fm < 4; ++fm)
        af[fm] = *(const bf16x8*)(smc + (wm * 64 + fm * 16 + l15) * 128 + slotoff);
#pragma unroll
      for (int fn = 0; fn < 4; ++fn)
        bfr[fn] = *(const bf16x8*)(smc + 16384 + (wn * 64 + fn * 16 + l15) * 128 + slotoff);
#pragma unroll
      for (int fm = 0; fm < 4; ++fm)
#pragma unroll
        for (int fn = 0; fn < 4; ++fn)
          acc[fm][fn] = __builtin_amdgcn_mfma_f32_16x16x32_bf16(
              af[fm], bfr[fn], acc[fm][fn], 0, 0, 0);
    }
  }

  const int colb = by * 128 + wn * 64;
#pragma unroll
  for (int fn = 0; fn < 4; ++fn) {
    const int col = colb + fn * 16 + l15;
    const float bias = gb[col];
#pragma unroll
    for (int fm = 0; fm < 4; ++fm) {
      const int rowb = bx * 128 + wm * 64 + fm * 16 + g * 4;
#pragma unroll
      for (int v = 0; v < 4; ++v)
        out[(size_t)(rowb + v) * E_DIM + col] = f2bf(acc[fm][fn][v] + bias);
    }
  }
}

// ---------------------------------------------------------------------------
// Per-row inverse L2 norm of bf16 [rows][512] -> invn[row] (f32).
// One wave per row (64 lanes x 16B = 1KB row).
// ---------------------------------------------------------------------------
__global__ __launch_bounds__(256) void rownorm_inv(
    const uint16_t* __restrict__ eg, float* __restrict__ invn) {
  const int row = blockIdx.x * 4 + (threadIdx.x >> 6);
  const int l = threadIdx.x & 63;
  const uint16_t* p = eg + (size_t)row * E_DIM + l * 8;
  uint4 v = *(const uint4*)p;
  uint32_t wd[4] = {v.x, v.y, v.z, v.w};
  float s = 0.f;
#pragma unroll
  for (int i = 0; i < 4; ++i) {
    float a = __builtin_bit_cast(float, (wd[i] & 0xFFFFu) << 16);
    float b = __builtin_bit_cast(float, wd[i] & 0xFFFF0000u);
    s += a * a + b * b;
  }
#pragma unroll
  for (int m = 1; m < 64; m <<= 1) s += __shfl_xor(s, m);
  if (l == 0) invn[row] = 1.0f / fmaxf(sqrtf(s), 1e-12f);
}

// ---------------------------------------------------------------------------
// Main fused kernel, 256x256 tile, 8 waves, BK=64, dbuf 128 KiB LDS,
// phase-interleaved (T3+T4+T5). Epilogue: a = S*ix*id; a^3*r2 summed over
// cols = ix^3 * sum(S^3 * id^3 * r2); atomicAdd into echo.
// ---------------------------------------------------------------------------
__global__ __launch_bounds__(512, 2) void minerva_main256(
    const uint16_t* __restrict__ Eg, const float* __restrict__ invn,
    const float* __restrict__ rin, float* __restrict__ echo) {
  extern __shared__ __align__(16) char smem[];
  const uint16_t* Xn = Eg;
  const uint16_t* Dn = Eg + (size_t)N_ROWS * E_DIM;
  const float* invx = invn;
  const float* invd = invn + N_ROWS;

  const int t_ = threadIdx.x;
  const int l = t_ & 63, w = t_ >> 6;
  const int wm = w >> 2, wn = w & 3;
  const int bx = blockIdx.x, by = blockIdx.y;
  const int g = l >> 4, x7 = l & 7, l15 = l & 15;

  f32x4 acc[8][4];
#pragma unroll
  for (int a_ = 0; a_ < 8; ++a_)
#pragma unroll
    for (int b_ = 0; b_ < 4; ++b_) acc[a_][b_] = (f32x4){0.f, 0.f, 0.f, 0.f};

  const int rr = t_ >> 3, ss = t_ & 7;
  const int s0 = ss ^ (rr & 7);
  const uint16_t* gA = Xn + (size_t)(bx * 256 + rr) * E_DIM + s0 * 8;
  const uint16_t* gB = Dn + (size_t)(by * 256 + rr) * E_DIM + s0 * 8;
  char* ldsDst = smem + t_ * 16;

#define STG_A(CUR, KK, I) GLOAD_LDS16(gA + (size_t)(I) * 64 * E_DIM + (KK), \
                                      ldsDst + (CUR) * 32768 + (I) * 8192)
#define STG_B(CUR, KK, I) GLOAD_LDS16(gB + (size_t)(I) * 64 * E_DIM + (KK), \
                                      ldsDst + 65536 + (CUR) * 32768 + (I) * 8192)

#define PHASE(FM0, KS, READ_B, GL, LAST)                                       \
  {                                                                            \
    const int so = (((KS) * 4 + g) ^ x7) << 4;                                 \
    bf16x8 af[4];                                                              \
    _Pragma("unroll") for (int i_ = 0; i_ < 4; ++i_)                           \
        af[i_] = *(const bf16x8*)(bufA +                                       \
                  (wm * 128 + ((FM0) + i_) * 16 + l15) * 128 + so);            \
    if (READ_B) {                                                              \
      _Pragma("unroll") for (int j_ = 0; j_ < 4; ++j_)                         \
          bfr[j_] = *(const bf16x8*)(bufB +                                    \
                    (wn * 64 + j_ * 16 + l15) * 128 + so);                     \
    }                                                                          \
    GL;                                                                        \
    __builtin_amdgcn_s_barrier();                                              \
    __builtin_amdgcn_s_setprio(1);                                             \
    _Pragma("unroll") for (int i_ = 0; i_ < 4; ++i_)                           \
        _Pragma("unroll") for (int j_ = 0; j_ < 4; ++j_)                       \
            acc[(FM0) + i_][j_] = __builtin_amdgcn_mfma_f32_16x16x32_bf16(     \
                af[i_], bfr[j_], acc[(FM0) + i_][j_], 0, 0, 0);                \
    __builtin_amdgcn_s_setprio(0);                                             \
    if (LAST) asm volatile("s_waitcnt vmcnt(0)" ::: "memory");                 \
    __builtin_amdgcn_s_barrier();                                              \
  }

#define TILE(KKN, CUR, PF)                                                     \
  {                                                                            \
    char* bufA = smem + (CUR) * 32768;                                         \
    char* bufB = smem + 65536 + (CUR) * 32768;                                 \
    bf16x8 bfr[4];                                                             \
    PHASE(0, 0, 1, if (PF) { STG_A(1 - (CUR), KKN, 0); STG_A(1 - (CUR), KKN, 1); }, 0) \
    PHASE(4, 0, 0, if (PF) { STG_A(1 - (CUR), KKN, 2); STG_A(1 - (CUR), KKN, 3); }, 0) \
    PHASE(0, 1, 1, if (PF) { STG_B(1 - (CUR), KKN, 0); STG_B(1 - (CUR), KKN, 1); }, 0) \
    PHASE(4, 1, 0, if (PF) { STG_B(1 - (CUR), KKN, 2); STG_B(1 - (CUR), KKN, 3); }, 1) \
  }

  STG_A(0, 0, 0); STG_A(0, 0, 1); STG_A(0, 0, 2); STG_A(0, 0, 3);
  STG_B(0, 0, 0); STG_B(0, 0, 1); STG_B(0, 0, 2); STG_B(0, 0, 3);
  asm volatile("s_waitcnt vmcnt(0)" ::: "memory");
  __builtin_amdgcn_s_barrier();

  for (int t2 = 0; t2 < 8; t2 += 2) {
    TILE((t2 + 1) * 64, 0, 1);
    const int pf2 = (t2 < 6);
    TILE((t2 + 2) * 64, 1, pf2);
  }

  // Epilogue: per-col factor c = id^3 * r2; reduce S^3*c over cols; * ix^3.
  const int jb = by * 256 + wn * 64;
  float c[4];
#pragma unroll
  for (int fn = 0; fn < 4; ++fn) {
    const int col = jb + fn * 16 + l15;
    const float id = invd[col];
    const float r2 = rin[col] * 2.0f - 1.0f;
    c[fn] = id * id * id * r2;
  }
  const int rowb = bx * 256 + wm * 128;
#pragma unroll
  for (int fm = 0; fm < 8; ++fm) {
#pragma unroll
    for (int v = 0; v < 4; ++v) {
      float sum = 0.f;
#pragma unroll
      for (int fn = 0; fn < 4; ++fn) {
        const float a = acc[fm][fn][v];
        sum += a * a * a * c[fn];
      }
      sum += __shfl_xor(sum, 1);
      sum += __shfl_xor(sum, 2);
      sum += __shfl_xor(sum, 4);
      sum += __shfl_xor(sum, 8);
      if (l15 == 0) {
        const int row = rowb + fm * 16 + g * 4 + v;
        const float ix = invx[row];
        atomicAdd(&echo[row], sum * ix * ix * ix);
      }
    }
  }
#undef STG_A
#undef STG_B
#undef PHASE
#undef TILE
}

// ---------------------------------------------------------------------------
__global__ __launch_bounds__(256) void head_sigmoid(
    const float* __restrict__ echo, const float* __restrict__ hw,
    const float* __restrict__ hb, float* __restrict__ out, int n) {
  const int i = blockIdx.x * 256 + threadIdx.x;
  if (i < n) {
    const float e = echo[i] * hw[0] + hb[0];
    out[i] = 1.0f / (1.0f + __expf(-e));
  }
}

// ---------------------------------------------------------------------------
extern "C" void kernel_launch(void* const* d_in, const int* in_sizes, int n_in,
                              void* d_out, int out_size, void* d_ws, size_t ws_size,
                              hipStream_t stream) {
  const float* X  = (const float*)d_in[0];
  const float* D  = (const float*)d_in[1];
  const float* r  = (const float*)d_in[2];
  const float* gw = (const float*)d_in[3];
  const float* gb = (const float*)d_in[4];
  const float* hw = (const float*)d_in[5];
  const float* hb = (const float*)d_in[6];
  float* out = (float*)d_out;

  // ws layout
  uint16_t* cat  = (uint16_t*)d_ws;                       // [24576][768] bf16
  uint16_t* gwb  = cat + (size_t)T_ROWS * F_DIM;          // [512][768] bf16
  uint16_t* Eg   = gwb + (size_t)E_DIM * F_DIM;           // [24576][512] bf16
  float*    invn = (float*)(Eg + (size_t)T_ROWS * E_DIM); // [24576] f32
  float*    echo = invn + T_ROWS;                         // [8192] f32

  hipMemsetAsync(echo, 0, (size_t)N_ROWS * sizeof(float), stream);

  (void)hipFuncSetAttribute((const void*)minerva_main256,
                            hipFuncAttributeMaxDynamicSharedMemorySize, 131072);

  dim3 blk(256);
  cvt_f32_bf16<<<2048, blk, 0, stream>>>(X, cat, N_ROWS * F_DIM / 8);
  cvt_f32_bf16<<<2048, blk, 0, stream>>>(D, cat + (size_t)N_ROWS * F_DIM,
                                         M_ROWS * F_DIM / 8);
  cvt_f32_bf16<<<192, blk, 0, stream>>>(gw, gwb, E_DIM * F_DIM / 8);

  embed_gemm_bf<<<dim3(T_ROWS / 128, E_DIM / 128), blk, 0, stream>>>(cat, gwb, gb, Eg);
  rownorm_inv<<<T_ROWS / 4, blk, 0, stream>>>(Eg, invn);

  minerva_main256<<<dim3(N_ROWS / 256, M_ROWS / 256), dim3(512), 131072, stream>>>(
      Eg, invn, r, echo);
  head_sigmoid<<<(N_ROWS + 255) / 256, blk, 0, stream>>>(echo, hw, hb, out, N_ROWS);
}